// Round 1
// baseline (698.140 us; speedup 1.0000x reference)
//
#include <hip/hip_runtime.h>
#include <math.h>

// DotAttention: context[b,f] = sum_t softmax_t(<hd[b],he[b,t]>) * he[b,t,f]
// One-pass flash-style. he (512 MiB > L3) streamed exactly once via
// async global->LDS DMA, 2-tiles-deep prefetch with counted vmcnt waits
// (raw s_barrier, never drain to 0 mid-loop). Wave w owns row w's dot
// (no redundant compute); scores broadcast via 16 B of LDS.

#define BB 64
#define TT 2048
#define FF 1024
#define RR 4          // rows per tile (16 KiB tile)
#define NBUF 3        // triple-buffer -> prefetch depth 2 tiles

typedef __attribute__((address_space(1))) const void* gas_ptr;
typedef __attribute__((address_space(3))) void* las_ptr;

// async 16B-per-lane global->LDS: LDS dest = wave-uniform base + lane*16
__device__ __forceinline__ void gld_lds16(const float* g, float* l) {
    __builtin_amdgcn_global_load_lds((gas_ptr)g, (las_ptr)l, 16, 0, 0);
}

// stage one 4 KiB he row into LDS: 4 x 1 KiB DMA per wave
__device__ __forceinline__ void stage_row(const float* __restrict__ row,
                                          float* dst, int lane) {
#pragma unroll
    for (int k = 0; k < 4; ++k)
        gld_lds16(row + k * 256 + lane * 4, dst + k * 256);
}

__global__ __launch_bounds__(256) void attn_pass1(
    const float* __restrict__ hd, const float* __restrict__ he,
    float* __restrict__ part_ctx, float* __restrict__ part_m,
    float* __restrict__ part_l, int S, int Tc)
{
    const int bid  = blockIdx.x;
    const int b    = bid / S;
    const int s    = bid - b * S;
    const int t0   = s * Tc;
    const int lane = threadIdx.x & 63;
    const int wave = threadIdx.x >> 6;
    const int nt   = Tc / RR;           // >= 2 for all S used here

    __shared__ __align__(16) float buf[NBUF][RR * FF];   // 48 KiB
    __shared__ __align__(16) float scores[RR];

    // hd[b] fragment matching the dot read layout: elements 4*lane + 256*k
    const float* hdb = hd + (size_t)b * FF;
    float4 hdv[4];
#pragma unroll
    for (int k = 0; k < 4; ++k)
        hdv[k] = *(const float4*)(hdb + 4 * lane + 256 * k);

    const float* heb = he + ((size_t)b * TT + t0) * (size_t)FF;

    float m = -INFINITY, l = 0.f;
    float4 ctx = make_float4(0.f, 0.f, 0.f, 0.f);

    // prologue: stage tiles 0 and 1 (wave w stages row w of each tile)
    stage_row(heb + (size_t)wave * FF, &buf[0][wave * FF], lane);
    stage_row(heb + (size_t)(RR + wave) * FF, &buf[1][wave * FF], lane);

    for (int kt = 0; kt < nt; ++kt) {
        const int cur = kt % NBUF;

        // ---- A: own DMA for tile kt retired (counted — tile kt+1 stays in
        //         flight), then block barrier => buf[cur] valid for all waves
        //         and buf[(kt-1)%NBUF] is dead (readers consumed pre-barrier).
        if (kt + 1 < nt) {
            asm volatile("s_waitcnt vmcnt(4)" ::: "memory");
        } else {
            asm volatile("s_waitcnt vmcnt(0)" ::: "memory");
        }
        __builtin_amdgcn_sched_barrier(0);
        __builtin_amdgcn_s_barrier();
        __builtin_amdgcn_sched_barrier(0);

        // ---- B: prefetch tile kt+2 into the slot tile kt-1 just freed.
        if (kt + 2 < nt)
            stage_row(heb + ((size_t)(kt + 2) * RR + wave) * FF,
                      &buf[(kt + 2) % NBUF][wave * FF], lane);

        // ---- C: wave w computes the dot of row w only (no redundancy).
        {
            const float* rp = &buf[cur][wave * FF];
            float4 hv[4];
#pragma unroll
            for (int k = 0; k < 4; ++k)
                hv[k] = *(const float4*)(rp + 4 * lane + 256 * k);
            float acc = 0.f;
#pragma unroll
            for (int k = 0; k < 4; ++k)
                acc += hdv[k].x * hv[k].x + hdv[k].y * hv[k].y +
                       hdv[k].z * hv[k].z + hdv[k].w * hv[k].w;
#pragma unroll
            for (int off = 32; off >= 1; off >>= 1)
                acc += __shfl_xor(acc, off, 64);
            if (lane == 0) scores[wave] = acc;
        }

        // ---- D: commit score writes, lgkm-only barrier (DMA queue untouched).
        asm volatile("s_waitcnt lgkmcnt(0)" ::: "memory");
        __builtin_amdgcn_sched_barrier(0);
        __builtin_amdgcn_s_barrier();
        __builtin_amdgcn_sched_barrier(0);

        // ---- E: block-wide online-softmax update + ctx accumulate.
        const float4 sc = *(const float4*)scores;
        float mn = fmaxf(fmaxf(m, fmaxf(sc.x, sc.y)), fmaxf(sc.z, sc.w));
        const float alpha = __expf(m - mn);   // exp(-inf)=0 on first tile
        const float w0 = __expf(sc.x - mn), w1 = __expf(sc.y - mn);
        const float w2 = __expf(sc.z - mn), w3 = __expf(sc.w - mn);

        const int f4 = threadIdx.x * 4;       // this thread's f-slice
        const float4 r0 = *(const float4*)&buf[cur][0 * FF + f4];
        const float4 r1 = *(const float4*)&buf[cur][1 * FF + f4];
        const float4 r2 = *(const float4*)&buf[cur][2 * FF + f4];
        const float4 r3 = *(const float4*)&buf[cur][3 * FF + f4];
        ctx.x = ctx.x * alpha + w0 * r0.x + w1 * r1.x + w2 * r2.x + w3 * r3.x;
        ctx.y = ctx.y * alpha + w0 * r0.y + w1 * r1.y + w2 * r2.y + w3 * r3.y;
        ctx.z = ctx.z * alpha + w0 * r0.z + w1 * r1.z + w2 * r2.z + w3 * r3.z;
        ctx.w = ctx.w * alpha + w0 * r0.w + w1 * r1.w + w2 * r2.w + w3 * r3.w;
        l = l * alpha + (w0 + w1 + w2 + w3);
        m = mn;
    }

    // per-thread slice is the block's partial — no cross-wave combine needed
    *(float4*)(part_ctx + (size_t)bid * FF + threadIdx.x * 4) = ctx;
    if (threadIdx.x == 0) { part_m[bid] = m; part_l[bid] = l; }
}

// Pass 2: combine S chunk-partials and normalize. 4 blocks per batch
// (each owns a 256-float slice) -> 256 blocks instead of 64.
__global__ __launch_bounds__(64) void attn_pass2(
    const float* __restrict__ part_ctx, const float* __restrict__ part_m,
    const float* __restrict__ part_l, float* __restrict__ out, int S)
{
    const int b  = blockIdx.x >> 2;
    const int f4 = ((blockIdx.x & 3) * 64 + threadIdx.x) * 4;

    float M = -INFINITY;
    for (int s = 0; s < S; ++s) M = fmaxf(M, part_m[b * S + s]);
    float L = 0.f;
    for (int s = 0; s < S; ++s)
        L += part_l[b * S + s] * __expf(part_m[b * S + s] - M);

    float4 acc = make_float4(0.f, 0.f, 0.f, 0.f);
    for (int s = 0; s < S; ++s) {
        const float e  = __expf(part_m[b * S + s] - M);
        const float4 c = *(const float4*)(part_ctx + ((size_t)(b * S + s)) * FF + f4);
        acc.x += e * c.x; acc.y += e * c.y; acc.z += e * c.z; acc.w += e * c.w;
    }
    const float inv = 1.f / L;
    *(float4*)(out + (size_t)b * FF + f4) =
        make_float4(acc.x * inv, acc.y * inv, acc.z * inv, acc.w * inv);
}

extern "C" void kernel_launch(void* const* d_in, const int* in_sizes, int n_in,
                              void* d_out, int out_size, void* d_ws, size_t ws_size,
                              hipStream_t stream) {
    const float* hd = (const float*)d_in[0];   // (64, 1024) f32
    const float* he = (const float*)d_in[1];   // (64, 2048, 1024) f32
    float* out = (float*)d_out;                // (64, 1024) f32

    // largest split count whose partials fit in the workspace
    int S = 32;
    while (S > 1 && (size_t)BB * S * (FF * sizeof(float) + 2 * sizeof(float)) > ws_size)
        S >>= 1;
    const int Tc = TT / S;   // 64 at S=32 -> 16 tiles of RR=4

    float* part_ctx = (float*)d_ws;                      // B*S*F
    float* part_m   = part_ctx + (size_t)BB * S * FF;    // B*S
    float* part_l   = part_m + (size_t)BB * S;           // B*S

    attn_pass1<<<BB * S, 256, 0, stream>>>(hd, he, part_ctx, part_m, part_l, S, Tc);
    attn_pass2<<<BB * 4, 64, 0, stream>>>(part_ctx, part_m, part_l, out, S);
}

// Round 2
// 695.549 us; speedup vs baseline: 1.0037x; 1.0037x over previous
//
#include <hip/hip_runtime.h>
#include <math.h>

// DotAttention: context[b,f] = sum_t softmax_t(<hd[b],he[b,t]>) * he[b,t,f]
// Register-streamed flash-style pass1: wave w owns row kt*4+w, staged to
// VGPRs with plain global_load_dwordx4 (NOT global_load_lds — the LDS-DMA
// path was measured pinned at ~1.6 TB/s on HBM-miss streams across two
// different schedules; plain loads hit ~6.3 TB/s per m13).
// Each wave runs an independent online-softmax chain (private m, l, and a
// full 1024-float ctx replica spread 16 floats/lane). Main loop has ZERO
// barriers and ZERO LDS ops -> no vmcnt drains, prefetch pipelines freely.
// The 4 wave chains merge once at block end through 16 KiB LDS.

#define BB 64
#define TT 2048
#define FF 1024

__global__ __launch_bounds__(256) void attn_pass1(
    const float* __restrict__ hd, const float* __restrict__ he,
    float* __restrict__ part_ctx, float* __restrict__ part_m,
    float* __restrict__ part_l, int S, int Tc)
{
    const int bid  = blockIdx.x;
    const int b    = bid / S;
    const int s    = bid - b * S;
    const int t0   = s * Tc;
    const int lane = threadIdx.x & 63;
    const int wave = threadIdx.x >> 6;
    const int nt   = Tc >> 2;          // 4 rows per iteration, one per wave

    __shared__ __align__(16) float cbuf[4][FF];   // end-of-block combine, 16 KiB
    __shared__ float wm[4], wl[4];

    // hd fragment at this lane's float4 slots: float4 index lane + 64k
    const float* hdb = hd + (size_t)b * FF;
    float4 hdv[4];
#pragma unroll
    for (int k = 0; k < 4; ++k)
        hdv[k] = *(const float4*)(hdb + 4 * (lane + 64 * k));

    const float* heb = he + ((size_t)b * TT + t0) * (size_t)FF;

    // this wave's private online-softmax state
    float m = -INFINITY, l = 0.f;
    float4 ctx[4];
#pragma unroll
    for (int k = 0; k < 4; ++k) ctx[k] = make_float4(0.f, 0.f, 0.f, 0.f);

    // prologue: load row `wave` into cur
    float4 cur[4], nxt[4];
    {
        const float* r0 = heb + (size_t)wave * FF;
#pragma unroll
        for (int k = 0; k < 4; ++k)
            cur[k] = *(const float4*)(r0 + 4 * (lane + 64 * k));
    }

    for (int kt = 0; kt < nt; ++kt) {
        // prefetch next row (depth 1): issued here, consumed next iteration
        if (kt + 1 < nt) {
            const float* rn = heb + ((size_t)(kt + 1) * 4 + wave) * FF;
#pragma unroll
            for (int k = 0; k < 4; ++k)
                nxt[k] = *(const float4*)(rn + 4 * (lane + 64 * k));
        }

        // dot of my wave's current row with hd[b]
        float d = 0.f;
#pragma unroll
        for (int k = 0; k < 4; ++k)
            d += hdv[k].x * cur[k].x + hdv[k].y * cur[k].y +
                 hdv[k].z * cur[k].z + hdv[k].w * cur[k].w;
#pragma unroll
        for (int off = 32; off >= 1; off >>= 1)
            d += __shfl_xor(d, off, 64);

        // private online-softmax update
        const float mn    = fmaxf(m, d);
        const float alpha = __expf(m - mn);   // exp(-inf)=0 on first tile
        const float w     = __expf(d - mn);
#pragma unroll
        for (int k = 0; k < 4; ++k) {
            ctx[k].x = ctx[k].x * alpha + w * cur[k].x;
            ctx[k].y = ctx[k].y * alpha + w * cur[k].y;
            ctx[k].z = ctx[k].z * alpha + w * cur[k].z;
            ctx[k].w = ctx[k].w * alpha + w * cur[k].w;
        }
        l = l * alpha + w;
        m = mn;

#pragma unroll
        for (int k = 0; k < 4; ++k) cur[k] = nxt[k];
    }

    // ---- merge the 4 independent wave chains ----
    if (lane == 0) { wm[wave] = m; wl[wave] = l; }
    __syncthreads();
    const float M = fmaxf(fmaxf(wm[0], wm[1]), fmaxf(wm[2], wm[3]));
    const float L = wl[0] * __expf(wm[0] - M) + wl[1] * __expf(wm[1] - M) +
                    wl[2] * __expf(wm[2] - M) + wl[3] * __expf(wm[3] - M);
    const float e = __expf(m - M);        // this wave's rescale factor
#pragma unroll
    for (int k = 0; k < 4; ++k) {
        float4 c = ctx[k];
        c.x *= e; c.y *= e; c.z *= e; c.w *= e;
        *(float4*)&cbuf[wave][4 * (lane + 64 * k)] = c;
    }
    __syncthreads();

    const int j = threadIdx.x;            // owns output float4 #j
    const float4 c0 = *(const float4*)&cbuf[0][4 * j];
    const float4 c1 = *(const float4*)&cbuf[1][4 * j];
    const float4 c2 = *(const float4*)&cbuf[2][4 * j];
    const float4 c3 = *(const float4*)&cbuf[3][4 * j];
    float4 o;
    o.x = c0.x + c1.x + c2.x + c3.x;
    o.y = c0.y + c1.y + c2.y + c3.y;
    o.z = c0.z + c1.z + c2.z + c3.z;
    o.w = c0.w + c1.w + c2.w + c3.w;
    *(float4*)(part_ctx + (size_t)bid * FF + 4 * j) = o;
    if (threadIdx.x == 0) { part_m[bid] = M; part_l[bid] = L; }
}

// Pass 2: combine S chunk-partials and normalize. 4 blocks per batch.
__global__ __launch_bounds__(64) void attn_pass2(
    const float* __restrict__ part_ctx, const float* __restrict__ part_m,
    const float* __restrict__ part_l, float* __restrict__ out, int S)
{
    const int b  = blockIdx.x >> 2;
    const int f4 = ((blockIdx.x & 3) * 64 + threadIdx.x) * 4;

    float M = -INFINITY;
    for (int s = 0; s < S; ++s) M = fmaxf(M, part_m[b * S + s]);
    float L = 0.f;
    for (int s = 0; s < S; ++s)
        L += part_l[b * S + s] * __expf(part_m[b * S + s] - M);

    float4 acc = make_float4(0.f, 0.f, 0.f, 0.f);
    for (int s = 0; s < S; ++s) {
        const float e  = __expf(part_m[b * S + s] - M);
        const float4 c = *(const float4*)(part_ctx + ((size_t)(b * S + s)) * FF + f4);
        acc.x += e * c.x; acc.y += e * c.y; acc.z += e * c.z; acc.w += e * c.w;
    }
    const float inv = 1.f / L;
    *(float4*)(out + (size_t)b * FF + f4) =
        make_float4(acc.x * inv, acc.y * inv, acc.z * inv, acc.w * inv);
}

extern "C" void kernel_launch(void* const* d_in, const int* in_sizes, int n_in,
                              void* d_out, int out_size, void* d_ws, size_t ws_size,
                              hipStream_t stream) {
    const float* hd = (const float*)d_in[0];   // (64, 1024) f32
    const float* he = (const float*)d_in[1];   // (64, 2048, 1024) f32
    float* out = (float*)d_out;                // (64, 1024) f32

    // largest split count whose partials fit in the workspace
    int S = 32;
    while (S > 1 && (size_t)BB * S * (FF * sizeof(float) + 2 * sizeof(float)) > ws_size)
        S >>= 1;
    const int Tc = TT / S;   // 64 at S=32 -> nt=16 iterations of 4 rows

    float* part_ctx = (float*)d_ws;                      // B*S*F
    float* part_m   = part_ctx + (size_t)BB * S * FF;    // B*S
    float* part_l   = part_m + (size_t)BB * S;           // B*S

    attn_pass1<<<BB * S, 256, 0, stream>>>(hd, he, part_ctx, part_m, part_l, S, Tc);
    attn_pass2<<<BB * 4, 64, 0, stream>>>(part_ctx, part_m, part_l, out, S);
}